// Round 1
// 590.178 us; speedup vs baseline: 1.0316x; 1.0316x over previous
//
#include <hip/hip_runtime.h>
#include <hip/hip_bf16.h>
#include <stdint.h>

#define BATCH 8192
#define KDIM  4096   // IN_FEATURES
#define NDIM  4096   // OUT_FEATURES

// GEMM tile config: 256x256 tile, BK=32, 8 waves (2x4), per-wave 128x64.
#define BM 256
#define BN 256
#define BK 32
#define NTILES (KDIM / BK)   // 128

typedef __bf16 bf16x8 __attribute__((ext_vector_type(8)));
typedef float  f32x4  __attribute__((ext_vector_type(4)));

__device__ inline float bf2f(uint32_t h) {
    union { uint32_t u; float f; } c; c.u = h << 16; return c.f;
}
__device__ inline uint32_t pk2(float a, float b) {
    union { __hip_bfloat16 h[2]; uint32_t u; } o;
    o.h[0] = __float2bfloat16(a); o.h[1] = __float2bfloat16(b);
    return o.u;
}

// ---------------------------------------------------------------------------
// Kernel 0: detect dtypes device-side (graph-safe, deterministic). UNCHANGED.
// flags[0]: 1 if x is fp32, 0 if bf16
// flags[1]: 1 if w is fp32, 0 if bf16
// flags[2]: mask enc: 0=int32{0,1}, 1=uint8 bytes, 2=bf16 halves, 3=fp32 {0,1.0f}
// ---------------------------------------------------------------------------
__global__ void detect_kernel(const uint32_t* __restrict__ x,
                              const uint32_t* __restrict__ w,
                              const uint32_t* __restrict__ m,
                              int* __restrict__ flags) {
    __shared__ int cx, cw, all01, allf32, anybf16;
    if (threadIdx.x == 0) { cx = 0; cw = 0; all01 = 1; allf32 = 1; anybf16 = 0; }
    __syncthreads();
    int lcx = 0, lcw = 0, la01 = 1, laf = 1, lab = 0;
    #pragma unroll
    for (int jj = 0; jj < 16; ++jj) {
        int i = jj * 256 + threadIdx.x;
        uint32_t vx = x[i], vw = w[i], vm = m[i];
        uint32_t ex = (vx >> 7) & 0xFFu; if (ex >= 0x70u && ex <= 0x86u) lcx++;
        uint32_t ew = (vw >> 7) & 0xFFu; if (ew >= 0x70u && ew <= 0x86u) lcw++;
        if (vm > 1u) la01 = 0;
        if (vm != 0u && vm != 0x3F800000u) laf = 0;
        if ((vm & 0xFFFFu) == 0x3F80u || (vm >> 16) == 0x3F80u) lab = 1;
    }
    atomicAdd(&cx, lcx); atomicAdd(&cw, lcw);
    if (!la01) atomicAnd(&all01, 0);
    if (!laf)  atomicAnd(&allf32, 0);
    if (lab)   atomicOr(&anybf16, 1);
    __syncthreads();
    if (threadIdx.x == 0) {
        flags[0] = (cx < 2048) ? 1 : 0;
        flags[1] = (cw < 2048) ? 1 : 0;
        int f;
        if (all01)        f = 0;
        else if (allf32)  f = 3;
        else if (anybf16) f = 2;
        else              f = 1;
        flags[2] = f;
    }
}

// ---------------------------------------------------------------------------
// Kernel 1: x fp32 -> bf16. UNCHANGED.
// ---------------------------------------------------------------------------
__global__ void xconv_kernel(const float4* __restrict__ xf,
                             uint2* __restrict__ xb2,
                             const int* __restrict__ flags) {
    if (flags[0] == 0) return;             // x already bf16; GEMM reads it directly
    const int t = blockIdx.x * 256 + threadIdx.x;
    float4 a = xf[t];
    uint2 o; o.x = pk2(a.x, a.y); o.y = pk2(a.z, a.w);
    xb2[t] = o;
}

// ---------------------------------------------------------------------------
// Kernel 2: wm = bf16(w * mask). UNCHANGED.
// ---------------------------------------------------------------------------
__global__ void wmask_kernel(const void* __restrict__ w,
                             const void* __restrict__ mask,
                             const int*  __restrict__ flags,
                             uint2* __restrict__ wm2) {
    const int fw = flags[1], fm = flags[2];
    const int t = blockIdx.x * 256 + threadIdx.x;
    float wv[4];
    if (fw) {
        float4 a = ((const float4*)w)[t];
        wv[0] = a.x; wv[1] = a.y; wv[2] = a.z; wv[3] = a.w;
    } else {
        uint2 wb = ((const uint2*)w)[t];
        wv[0] = bf2f(wb.x & 0xFFFFu); wv[1] = bf2f(wb.x >> 16);
        wv[2] = bf2f(wb.y & 0xFFFFu); wv[3] = bf2f(wb.y >> 16);
    }
    int kb[4];
    if (fm == 1) {                       // uint8 bool bytes: 4 B per thread
        uint32_t m1 = ((const uint32_t*)mask)[t];
        kb[0] = (m1 & 0xFFu) != 0u;         kb[1] = ((m1 >> 8) & 0xFFu) != 0u;
        kb[2] = ((m1 >> 16) & 0xFFu) != 0u; kb[3] = (m1 >> 24) != 0u;
    } else if (fm == 2) {                // bf16 halves: 8 B per thread
        uint2 m2 = ((const uint2*)mask)[t];
        kb[0] = (m2.x & 0xFFFFu) != 0u; kb[1] = (m2.x >> 16) != 0u;
        kb[2] = (m2.y & 0xFFFFu) != 0u; kb[3] = (m2.y >> 16) != 0u;
    } else {                             // int32 {0,1} or fp32 {0,1.0f}: 16 B
        uint4 m4 = ((const uint4*)mask)[t];
        kb[0] = m4.x != 0u; kb[1] = m4.y != 0u; kb[2] = m4.z != 0u; kb[3] = m4.w != 0u;
    }
    uint2 o;
    o.x = pk2(kb[0] ? wv[0] : 0.0f, kb[1] ? wv[1] : 0.0f);
    o.y = pk2(kb[2] ? wv[2] : 0.0f, kb[3] ? wv[3] : 0.0f);
    wm2[t] = o;
}

// ---------------------------------------------------------------------------
// Kernel 3: 256x256 bf16 GEMM, C[M,N] = A[M,K] * B[N,K]^T
//   - 8 waves (512 thr), per-wave 128x64 output (8x4 frags of 16x16x32 MFMA)
//   - BK=32; 4-deep quad-buffered LDS (4 x 32 KiB = 128 KiB)
//   - counted s_waitcnt vmcnt(12): loads for tile kt+3 issued during kt,
//     NEVER drained to 0 in the main loop (T3+T4)
//   - LDS XOR-swizzle (T2): two 64-B rows per 128-B line, 16B-slot ^= line&7.
//     Swizzle applied on the *global source address* (global_load_lds writes
//     linearly) and on the ds_read address — same involution both sides.
//   - raw s_barrier (2 per tile), s_setprio(1) around the MFMA cluster (T5)
//   - XCD-aware block swizzle (T1): 512 wgs, 64 per XCD, A-panel-major
// Accumulation order over K identical to previous kernel (BK=32 ascending,
// same MFMA shape) -> numerics unchanged.
// ---------------------------------------------------------------------------
__global__ __launch_bounds__(512, 2)
void gemm_bt_kernel(const uint16_t* __restrict__ Araw, // x bf16 bits (if fx==0)
                    const uint16_t* __restrict__ Aconv,// xb in ws (if fx==1)
                    const uint16_t* __restrict__ B,    // wm bf16 bits [N,K]
                    void* __restrict__ Cout,
                    const int* __restrict__ flags) {
    // [0,64K): A buffers 4 x 16 KiB   [64K,128K): B buffers 4 x 16 KiB
    __shared__ char smem[131072];

    const int fx = flags[0];
    const uint16_t* A = fx ? Aconv : Araw;

    // T1: XCD swizzle. 512 blocks, 8 XCDs -> 64 contiguous tiles per XCD,
    // walking bn within a bm (A-panel reuse in per-XCD L2).
    const int bid = blockIdx.x;
    const int wid = (bid & 7) * 64 + (bid >> 3);
    const int m0  = (wid >> 4) * BM;    // 32 row panels
    const int n0  = (wid & 15) * BN;    // 16 col panels

    const int tid  = threadIdx.x;
    const int lane = tid & 63;
    const int wave = tid >> 6;          // 0..7; wave-row = wave>>2, wave-col = wave&3

    // ---- staging address precompute ----
    // Each 1 KiB LDS block = 8 lines of 128 B = 16 rows x 32 k (paired rows).
    // Lane l writes dest (line = l>>3, slot = l&7); source slot = dest^line.
    const int l3  = lane >> 3;
    const int ss  = (lane & 7) ^ l3;    // bit2 = row parity, low2 = k-slot
    const int par = ss >> 2;
    const int ks  = ss & 3;
    const size_t K2 = (size_t)KDIM * 2;

    const char* aSrc[2]; const char* bSrc[2];
    uint32_t aDst[2], bDst[2];
    #pragma unroll
    for (int c = 0; c < 2; ++c) {
        const int row = c * 128 + wave * 16 + 2 * l3 + par;   // 0..255, bijective
        aSrc[c] = (const char*)A + (size_t)(m0 + row) * K2 + ks * 16;
        bSrc[c] = (const char*)B + (size_t)(n0 + row) * K2 + ks * 16;
        aDst[c] = (uint32_t)((c * 8 + wave) * 1024);
        bDst[c] = (uint32_t)(65536 + (c * 8 + wave) * 1024);
    }

    auto issue = [&](uint32_t bufOff, int kts) {
        const size_t kb = (size_t)kts * 64;   // BK=32 bf16 = 64 B per row
        #pragma unroll
        for (int c = 0; c < 2; ++c) {
            __builtin_amdgcn_global_load_lds(
                (__attribute__((address_space(1))) void*)(aSrc[c] + kb),
                (__attribute__((address_space(3))) void*)(smem + bufOff + aDst[c]),
                16, 0, 0);
            __builtin_amdgcn_global_load_lds(
                (__attribute__((address_space(1))) void*)(bSrc[c] + kb),
                (__attribute__((address_space(3))) void*)(smem + bufOff + bDst[c]),
                16, 0, 0);
        }
    };

    // ---- fragment-read precompute (swizzled ds_read_b128 addresses) ----
    const int fr  = lane & 15;          // row within 16-row frag
    const int skq = lane >> 4;          // k-slot (8 bf16 = 16 B each)
    const uint32_t slotRD = (uint32_t)((((fr & 1) << 2) | skq) ^ (fr >> 1)) << 4;
    const uint32_t aRd = (uint32_t)(((wave >> 2) * 64 + (fr >> 1)) * 128) + slotRD;
    const uint32_t bRd = 65536u + (uint32_t)(((wave & 3) * 32 + (fr >> 1)) * 128) + slotRD;

    f32x4 acc[8][4] = {};
    uint32_t o0 = 0, o1 = 16384, o2 = 32768, o3 = 49152;

    // prologue: 3 tiles in flight before first compute
    issue(o0, 0); issue(o1, 1); issue(o2, 2);

    for (int kt = 0; kt < NTILES; ++kt) {
        // T3+T4: issue tile kt+3, wait COUNTED (12 = 3 tiles x 4 loads in flight)
        if (kt < NTILES - 3) {
            issue(o3, kt + 3);
            asm volatile("s_waitcnt vmcnt(12)" ::: "memory");
        } else if (kt == NTILES - 3) {
            asm volatile("s_waitcnt vmcnt(8)" ::: "memory");
        } else if (kt == NTILES - 2) {
            asm volatile("s_waitcnt vmcnt(4)" ::: "memory");
        } else {
            asm volatile("s_waitcnt vmcnt(0)" ::: "memory");
        }
        __builtin_amdgcn_s_barrier();        // tile kt staged & visible to all waves
        asm volatile("" ::: "memory");       // fence: no ds_read hoists above barrier

        bf16x8 af[8], bf[4];
        #pragma unroll
        for (int mi = 0; mi < 8; ++mi)
            af[mi] = *(const bf16x8*)(smem + o0 + aRd + mi * 1024);
        #pragma unroll
        for (int ni = 0; ni < 4; ++ni)
            bf[ni] = *(const bf16x8*)(smem + o0 + bRd + ni * 1024);

        __builtin_amdgcn_s_setprio(1);       // T5
        #pragma unroll
        for (int mi = 0; mi < 8; ++mi)
            #pragma unroll
            for (int ni = 0; ni < 4; ++ni)
                acc[mi][ni] = __builtin_amdgcn_mfma_f32_16x16x32_bf16(
                    af[mi], bf[ni], acc[mi][ni], 0, 0, 0);
        __builtin_amdgcn_s_setprio(0);

        asm volatile("" ::: "memory");       // fence: no ds_read sinks below barrier
        __builtin_amdgcn_s_barrier();        // all waves done reading buf(kt)

        const uint32_t t = o0; o0 = o1; o1 = o2; o2 = o3; o3 = t;
    }

    // Epilogue: D mapping col = lane&15, row = (lane>>4)*4 + reg
    const int cn  = lane & 15;
    const int rq  = lane >> 4;
    const int gmb = m0 + (wave >> 2) * 128;
    const int gnb = n0 + (wave & 3) * 64;
    if (fx) {
        float* C = (float*)Cout;
        #pragma unroll
        for (int mi = 0; mi < 8; ++mi)
            #pragma unroll
            for (int ni = 0; ni < 4; ++ni)
                #pragma unroll
                for (int r = 0; r < 4; ++r) {
                    const int gm = gmb + mi * 16 + rq * 4 + r;
                    const int gn = gnb + ni * 16 + cn;
                    C[(size_t)gm * NDIM + gn] = acc[mi][ni][r];
                }
    } else {
        __hip_bfloat16* C = (__hip_bfloat16*)Cout;
        #pragma unroll
        for (int mi = 0; mi < 8; ++mi)
            #pragma unroll
            for (int ni = 0; ni < 4; ++ni)
                #pragma unroll
                for (int r = 0; r < 4; ++r) {
                    const int gm = gmb + mi * 16 + rq * 4 + r;
                    const int gn = gnb + ni * 16 + cn;
                    C[(size_t)gm * NDIM + gn] = __float2bfloat16(acc[mi][ni][r]);
                }
    }
}

extern "C" void kernel_launch(void* const* d_in, const int* in_sizes, int n_in,
                              void* d_out, int out_size, void* d_ws, size_t ws_size,
                              hipStream_t stream) {
    const void* x    = d_in[0];   // [8192,4096] fp32 (or bf16) — detected on device
    const void* w    = d_in[1];   // [4096,4096] fp32 (or bf16)
    const void* mask = d_in[2];   // [4096,4096] bool — width detected on device

    // ws layout: flags (256 B) | wm bf16 (32 MiB) | xb bf16 (64 MiB)
    int*      flags = (int*)d_ws;
    uint16_t* wm    = (uint16_t*)((char*)d_ws + 256);
    uint16_t* xb    = (uint16_t*)((char*)d_ws + 256 + (size_t)NDIM * KDIM * 2);

    detect_kernel<<<1, 256, 0, stream>>>((const uint32_t*)x, (const uint32_t*)w,
                                         (const uint32_t*)mask, flags);

    // x conversion: 8192*4096/4 threads, 16 B load / 8 B store per thread
    xconv_kernel<<<(BATCH * KDIM / 4) / 256, 256, 0, stream>>>(
        (const float4*)x, (uint2*)xb, flags);

    // w*mask: 4096*4096/4 threads
    wmask_kernel<<<(NDIM * KDIM / 4) / 256, 256, 0, stream>>>(
        w, mask, flags, (uint2*)wm);

    // 512 workgroups (32 row-panels x 16 col-panels), 512 threads each
    gemm_bt_kernel<<<dim3((BATCH / BM) * (NDIM / BN)), 512, 0, stream>>>(
        (const uint16_t*)x, xb, wm, d_out, flags);
}

// Round 2
// 521.832 us; speedup vs baseline: 1.1667x; 1.1310x over previous
//
#include <hip/hip_runtime.h>
#include <hip/hip_bf16.h>
#include <stdint.h>

#define BATCH 8192
#define KDIM  4096   // IN_FEATURES
#define NDIM  4096   // OUT_FEATURES

// GEMM tile config: 256x256 tile, BK=64, 8 waves (2x4), per-wave 128x64,
// 8-phase schedule (m201 template), 2 K-tiles per unrolled iteration.
#define BM 256
#define BN 256
#define BK 64
#define NT (KDIM / BK)   // 64

typedef __bf16 bf16x8 __attribute__((ext_vector_type(8)));
typedef float  f32x4  __attribute__((ext_vector_type(4)));

__device__ inline float bf2f(uint32_t h) {
    union { uint32_t u; float f; } c; c.u = h << 16; return c.f;
}
__device__ inline uint32_t pk2(float a, float b) {
    union { __hip_bfloat16 h[2]; uint32_t u; } o;
    o.h[0] = __float2bfloat16(a); o.h[1] = __float2bfloat16(b);
    return o.u;
}

// ---------------------------------------------------------------------------
// Kernel 0: detect dtypes device-side (graph-safe, deterministic). UNCHANGED.
// ---------------------------------------------------------------------------
__global__ void detect_kernel(const uint32_t* __restrict__ x,
                              const uint32_t* __restrict__ w,
                              const uint32_t* __restrict__ m,
                              int* __restrict__ flags) {
    __shared__ int cx, cw, all01, allf32, anybf16;
    if (threadIdx.x == 0) { cx = 0; cw = 0; all01 = 1; allf32 = 1; anybf16 = 0; }
    __syncthreads();
    int lcx = 0, lcw = 0, la01 = 1, laf = 1, lab = 0;
    #pragma unroll
    for (int jj = 0; jj < 16; ++jj) {
        int i = jj * 256 + threadIdx.x;
        uint32_t vx = x[i], vw = w[i], vm = m[i];
        uint32_t ex = (vx >> 7) & 0xFFu; if (ex >= 0x70u && ex <= 0x86u) lcx++;
        uint32_t ew = (vw >> 7) & 0xFFu; if (ew >= 0x70u && ew <= 0x86u) lcw++;
        if (vm > 1u) la01 = 0;
        if (vm != 0u && vm != 0x3F800000u) laf = 0;
        if ((vm & 0xFFFFu) == 0x3F80u || (vm >> 16) == 0x3F80u) lab = 1;
    }
    atomicAdd(&cx, lcx); atomicAdd(&cw, lcw);
    if (!la01) atomicAnd(&all01, 0);
    if (!laf)  atomicAnd(&allf32, 0);
    if (lab)   atomicOr(&anybf16, 1);
    __syncthreads();
    if (threadIdx.x == 0) {
        flags[0] = (cx < 2048) ? 1 : 0;
        flags[1] = (cw < 2048) ? 1 : 0;
        int f;
        if (all01)        f = 0;
        else if (allf32)  f = 3;
        else if (anybf16) f = 2;
        else              f = 1;
        flags[2] = f;
    }
}

// ---------------------------------------------------------------------------
// Kernel 1: x fp32 -> bf16. UNCHANGED.
// ---------------------------------------------------------------------------
__global__ void xconv_kernel(const float4* __restrict__ xf,
                             uint2* __restrict__ xb2,
                             const int* __restrict__ flags) {
    if (flags[0] == 0) return;
    const int t = blockIdx.x * 256 + threadIdx.x;
    float4 a = xf[t];
    uint2 o; o.x = pk2(a.x, a.y); o.y = pk2(a.z, a.w);
    xb2[t] = o;
}

// ---------------------------------------------------------------------------
// Kernel 2: wm = bf16(w * mask). UNCHANGED.
// ---------------------------------------------------------------------------
__global__ void wmask_kernel(const void* __restrict__ w,
                             const void* __restrict__ mask,
                             const int*  __restrict__ flags,
                             uint2* __restrict__ wm2) {
    const int fw = flags[1], fm = flags[2];
    const int t = blockIdx.x * 256 + threadIdx.x;
    float wv[4];
    if (fw) {
        float4 a = ((const float4*)w)[t];
        wv[0] = a.x; wv[1] = a.y; wv[2] = a.z; wv[3] = a.w;
    } else {
        uint2 wb = ((const uint2*)w)[t];
        wv[0] = bf2f(wb.x & 0xFFFFu); wv[1] = bf2f(wb.x >> 16);
        wv[2] = bf2f(wb.y & 0xFFFFu); wv[3] = bf2f(wb.y >> 16);
    }
    int kb[4];
    if (fm == 1) {
        uint32_t m1 = ((const uint32_t*)mask)[t];
        kb[0] = (m1 & 0xFFu) != 0u;         kb[1] = ((m1 >> 8) & 0xFFu) != 0u;
        kb[2] = ((m1 >> 16) & 0xFFu) != 0u; kb[3] = (m1 >> 24) != 0u;
    } else if (fm == 2) {
        uint2 m2 = ((const uint2*)mask)[t];
        kb[0] = (m2.x & 0xFFFFu) != 0u; kb[1] = (m2.x >> 16) != 0u;
        kb[2] = (m2.y & 0xFFFFu) != 0u; kb[3] = (m2.y >> 16) != 0u;
    } else {
        uint4 m4 = ((const uint4*)mask)[t];
        kb[0] = m4.x != 0u; kb[1] = m4.y != 0u; kb[2] = m4.z != 0u; kb[3] = m4.w != 0u;
    }
    uint2 o;
    o.x = pk2(kb[0] ? wv[0] : 0.0f, kb[1] ? wv[1] : 0.0f);
    o.y = pk2(kb[2] ? wv[2] : 0.0f, kb[3] ? wv[3] : 0.0f);
    wm2[t] = o;
}

// ---------------------------------------------------------------------------
// Kernel 3: 256x256 bf16 GEMM, C = A[M,K] * B[N,K]^T — 8-phase schedule.
//   Per K-tile (BK=64): 4 phases (C-quadrants), each:
//     { ds_read subtile | issue 1 stage-unit (2 global_load_lds) | barrier |
//       lgkmcnt(0) | setprio(1) | 16 MFMA | setprio(0) | barrier }
//   Stage unit = one matrix-half (128 rows x 64 k = 16 KiB, 2 loads/thread).
//   Interleaved halves: wave's mi 0-3 <- A-half0, mi 4-7 <- A-half1;
//   ni 0-1 <- B-half0, ni 2-3 <- B-half1 (frees each half after its last
//   reading phase, so next-next tile's stage-unit can overwrite it).
//   Counted vmcnt(4) once per K-tile at phase 4 (2 SUs stay in flight).
//   Choreography (issue at tile v): ph1 A-h1(v+1), ph2 B-h1(v+1),
//   ph3 A-h0(v+2), ph4 B-h0(v+2). Certification: vmcnt(4)@ph4 drains
//   through B-h1(v+1) -> tile v+1 fully staged before its ph1 reads.
//   LDS XOR-swizzle on k-slot (slot ^= row&7), pre-swizzled global source.
//   Accumulation order over K identical to previous kernel (32-chunks
//   ascending) -> numerics unchanged.
// ---------------------------------------------------------------------------
__global__ __launch_bounds__(512, 2)
void gemm_bt_kernel(const uint16_t* __restrict__ Araw,
                    const uint16_t* __restrict__ Aconv,
                    const uint16_t* __restrict__ B,
                    void* __restrict__ Cout,
                    const int* __restrict__ flags) {
    // buffer p at p*65536: A halves at +0,+16384; B halves at +32768,+49152
    __shared__ char smem[131072];

    const int fx = flags[0];
    const uint16_t* A = fx ? Aconv : Araw;

    const int bid = blockIdx.x;
    const int wid = (bid & 7) * 64 + (bid >> 3);   // T1: 512 % 8 == 0, bijective
    const int m0  = (wid >> 4) * BM;
    const int n0  = (wid & 15) * BN;

    const int tid  = threadIdx.x;
    const int lane = tid & 63;
    const int wave = tid >> 6;
    const int wm_  = wave >> 2;    // 0..1
    const int wn_  = wave & 3;     // 0..3

    // ---- staging precompute (pre-swizzled global sources, linear LDS dest) ----
    const int tL = tid >> 3;                                   // dest line 0..63
    const uint32_t srcSlot = (uint32_t)(((tid & 7) ^ (tL & 7)) * 16);
    const size_t K2 = (size_t)KDIM * 2;
    const char* aS[2][2]; const char* bS[2][2];                // [half][c]
    #pragma unroll
    for (int h = 0; h < 2; ++h)
        #pragma unroll
        for (int c = 0; c < 2; ++c) {
            const int r = h * 128 + tL + c * 64;
            aS[h][c] = (const char*)A + (size_t)(m0 + r) * K2 + srcSlot;
            bS[h][c] = (const char*)B + (size_t)(n0 + r) * K2 + srcSlot;
        }
    const uint32_t wdst = (uint32_t)(wave * 1024);  // HW adds lane*16

#define ISSUE_A(P, H, V) do {                                                   \
    const size_t kb_ = (size_t)(V) * 128;                                       \
    __builtin_amdgcn_global_load_lds(                                           \
        (__attribute__((address_space(1))) void*)(aS[H][0] + kb_),              \
        (__attribute__((address_space(3))) void*)(smem + (P)*65536 + (H)*16384 + wdst), 16, 0, 0); \
    __builtin_amdgcn_global_load_lds(                                           \
        (__attribute__((address_space(1))) void*)(aS[H][1] + kb_),              \
        (__attribute__((address_space(3))) void*)(smem + (P)*65536 + (H)*16384 + 8192 + wdst), 16, 0, 0); \
} while (0)

#define ISSUE_B(P, H, V) do {                                                   \
    const size_t kb_ = (size_t)(V) * 128;                                       \
    __builtin_amdgcn_global_load_lds(                                           \
        (__attribute__((address_space(1))) void*)(bS[H][0] + kb_),              \
        (__attribute__((address_space(3))) void*)(smem + (P)*65536 + 32768 + (H)*16384 + wdst), 16, 0, 0); \
    __builtin_amdgcn_global_load_lds(                                           \
        (__attribute__((address_space(1))) void*)(bS[H][1] + kb_),              \
        (__attribute__((address_space(3))) void*)(smem + (P)*65536 + 32768 + (H)*16384 + 8192 + wdst), 16, 0, 0); \
} while (0)

    // ---- fragment-read precompute ----
    const int fr = lane & 15;
    const int lq = lane >> 4;
    const uint32_t swz0 = (uint32_t)(((0 + lq) ^ (fr & 7)) * 16);
    const uint32_t swz1 = (uint32_t)(((4 + lq) ^ (fr & 7)) * 16);
    const uint32_t aRow = (uint32_t)((wm_ * 64 + fr) * 128);
    const uint32_t bRow = (uint32_t)((wn_ * 32 + fr) * 128);

    bf16x8 a[4][2], b[4][2];
    f32x4 acc[8][4] = {};

#define RD_A(P, H) do {                                                         \
    _Pragma("unroll")                                                           \
    for (int mi = 0; mi < 4; ++mi) {                                            \
        a[mi][0] = *(const bf16x8*)(smem + (P)*65536 + (H)*16384 + mi*2048 + aRow + swz0); \
        a[mi][1] = *(const bf16x8*)(smem + (P)*65536 + (H)*16384 + mi*2048 + aRow + swz1); \
    }                                                                           \
} while (0)

#define RD_B(P, H) do {                                                         \
    _Pragma("unroll")                                                           \
    for (int ni = 0; ni < 2; ++ni) {                                            \
        b[(H)*2+ni][0] = *(const bf16x8*)(smem + (P)*65536 + 32768 + (H)*16384 + ni*2048 + bRow + swz0); \
        b[(H)*2+ni][1] = *(const bf16x8*)(smem + (P)*65536 + 32768 + (H)*16384 + ni*2048 + bRow + swz1); \
    }                                                                           \
} while (0)

#define MFMA_Q(M0, N0) do {                                                     \
    _Pragma("unroll")                                                           \
    for (int mi = 0; mi < 4; ++mi)                                              \
        _Pragma("unroll")                                                       \
        for (int ni = 0; ni < 2; ++ni) {                                        \
            acc[(M0)+mi][(N0)+ni] = __builtin_amdgcn_mfma_f32_16x16x32_bf16(    \
                a[mi][0], b[(N0)+ni][0], acc[(M0)+mi][(N0)+ni], 0, 0, 0);       \
            acc[(M0)+mi][(N0)+ni] = __builtin_amdgcn_mfma_f32_16x16x32_bf16(    \
                a[mi][1], b[(N0)+ni][1], acc[(M0)+mi][(N0)+ni], 0, 0, 0);       \
        }                                                                       \
} while (0)

#define BAR() do { asm volatile("" ::: "memory");                               \
    __builtin_amdgcn_s_barrier();                                               \
    asm volatile("" ::: "memory"); } while (0)

#define TILE(P, V) do {                                                         \
    /* phase 1: miL x niL */                                                    \
    RD_A(P, 0); RD_B(P, 0);                                                     \
    if ((V) + 1 < NT) ISSUE_A(1-(P), 1, (V)+1);                                 \
    asm volatile("s_waitcnt lgkmcnt(8)" ::: "memory");                          \
    BAR();                                                                      \
    asm volatile("s_waitcnt lgkmcnt(0)" ::: "memory");                          \
    __builtin_amdgcn_s_setprio(1);  MFMA_Q(0, 0);  __builtin_amdgcn_s_setprio(0); \
    BAR();                                                                      \
    /* phase 2: miL x niH */                                                    \
    RD_B(P, 1);                                                                 \
    if ((V) + 1 < NT) ISSUE_B(1-(P), 1, (V)+1);                                 \
    BAR();                                                                      \
    asm volatile("s_waitcnt lgkmcnt(0)" ::: "memory");                          \
    __builtin_amdgcn_s_setprio(1);  MFMA_Q(0, 2);  __builtin_amdgcn_s_setprio(0); \
    BAR();                                                                      \
    /* phase 3: miH x niL */                                                    \
    RD_A(P, 1);                                                                 \
    if ((V) + 2 < NT) ISSUE_A(P, 0, (V)+2);                                     \
    BAR();                                                                      \
    asm volatile("s_waitcnt lgkmcnt(0)" ::: "memory");                          \
    __builtin_amdgcn_s_setprio(1);  MFMA_Q(4, 0);  __builtin_amdgcn_s_setprio(0); \
    BAR();                                                                      \
    /* phase 4: miH x niH */                                                    \
    if ((V) + 2 < NT) ISSUE_B(P, 0, (V)+2);                                     \
    BAR();                                                                      \
    __builtin_amdgcn_s_setprio(1);  MFMA_Q(4, 2);  __builtin_amdgcn_s_setprio(0); \
    if ((V) < NT - 2) { asm volatile("s_waitcnt vmcnt(4)" ::: "memory"); }      \
    else              { asm volatile("s_waitcnt vmcnt(0)" ::: "memory"); }      \
    BAR();                                                                      \
} while (0)

    // prologue: tile0 complete + tile1 row-half0 units; certify tile0
    ISSUE_A(0, 0, 0); ISSUE_B(0, 0, 0); ISSUE_B(0, 1, 0); ISSUE_A(0, 1, 0);
    ISSUE_A(1, 0, 1); ISSUE_B(1, 0, 1);
    asm volatile("s_waitcnt vmcnt(4)" ::: "memory");
    BAR();

    for (int it = 0; it < NT; it += 2) {
        TILE(0, it);
        TILE(1, it + 1);
    }

#undef TILE
#undef BAR
#undef MFMA_Q
#undef RD_B
#undef RD_A
#undef ISSUE_B
#undef ISSUE_A

    // Epilogue. D frag mapping: col = lane&15, row = (lane>>4)*4 + reg.
    // acc[m][n]: gm = m0 + (m>>2)*128 + wm_*64 + (m&3)*16;
    //            gn = n0 + (n>>1)*128 + wn_*32 + (n&1)*16.
    const int cn = lane & 15;
    const int rq = lane >> 4;
    if (fx) {
        float* C = (float*)Cout;
        #pragma unroll
        for (int mi = 0; mi < 8; ++mi)
            #pragma unroll
            for (int ni = 0; ni < 4; ++ni)
                #pragma unroll
                for (int r = 0; r < 4; ++r) {
                    const int gm = m0 + (mi >> 2) * 128 + wm_ * 64 + (mi & 3) * 16 + rq * 4 + r;
                    const int gn = n0 + (ni >> 1) * 128 + wn_ * 32 + (ni & 1) * 16 + cn;
                    C[(size_t)gm * NDIM + gn] = acc[mi][ni][r];
                }
    } else {
        __hip_bfloat16* C = (__hip_bfloat16*)Cout;
        #pragma unroll
        for (int mi = 0; mi < 8; ++mi)
            #pragma unroll
            for (int ni = 0; ni < 4; ++ni)
                #pragma unroll
                for (int r = 0; r < 4; ++r) {
                    const int gm = m0 + (mi >> 2) * 128 + wm_ * 64 + (mi & 3) * 16 + rq * 4 + r;
                    const int gn = n0 + (ni >> 1) * 128 + wn_ * 32 + (ni & 1) * 16 + cn;
                    C[(size_t)gm * NDIM + gn] = __float2bfloat16(acc[mi][ni][r]);
                }
    }
}

extern "C" void kernel_launch(void* const* d_in, const int* in_sizes, int n_in,
                              void* d_out, int out_size, void* d_ws, size_t ws_size,
                              hipStream_t stream) {
    const void* x    = d_in[0];
    const void* w    = d_in[1];
    const void* mask = d_in[2];

    int*      flags = (int*)d_ws;
    uint16_t* wm    = (uint16_t*)((char*)d_ws + 256);
    uint16_t* xb    = (uint16_t*)((char*)d_ws + 256 + (size_t)NDIM * KDIM * 2);

    detect_kernel<<<1, 256, 0, stream>>>((const uint32_t*)x, (const uint32_t*)w,
                                         (const uint32_t*)mask, flags);

    xconv_kernel<<<(BATCH * KDIM / 4) / 256, 256, 0, stream>>>(
        (const float4*)x, (uint2*)xb, flags);

    wmask_kernel<<<(NDIM * KDIM / 4) / 256, 256, 0, stream>>>(
        w, mask, flags, (uint2*)wm);

    gemm_bt_kernel<<<dim3((BATCH / BM) * (NDIM / BN)), 512, 0, stream>>>(
        (const uint16_t*)x, xb, wm, d_out, flags);
}

// Round 3
// 505.518 us; speedup vs baseline: 1.2044x; 1.0323x over previous
//
#include <hip/hip_runtime.h>
#include <hip/hip_bf16.h>
#include <stdint.h>

#define BATCH 8192
#define KDIM  4096   // IN_FEATURES
#define NDIM  4096   // OUT_FEATURES

// GEMM tile config: 256x256 tile, BK=64, 8 waves (2x4), per-wave 128x64,
// 8-phase schedule, 2 K-tiles per unrolled iteration, 1 barrier per phase.
#define BM 256
#define BN 256
#define BK 64
#define NT (KDIM / BK)   // 64

typedef __bf16 bf16x8 __attribute__((ext_vector_type(8)));
typedef float  f32x4  __attribute__((ext_vector_type(4)));

__device__ inline float bf2f(uint32_t h) {
    union { uint32_t u; float f; } c; c.u = h << 16; return c.f;
}
__device__ inline uint32_t pk2(float a, float b) {
    union { __hip_bfloat16 h[2]; uint32_t u; } o;
    o.h[0] = __float2bfloat16(a); o.h[1] = __float2bfloat16(b);
    return o.u;
}

// ---------------------------------------------------------------------------
// Kernel 0: detect dtypes device-side (graph-safe, deterministic). UNCHANGED.
// ---------------------------------------------------------------------------
__global__ void detect_kernel(const uint32_t* __restrict__ x,
                              const uint32_t* __restrict__ w,
                              const uint32_t* __restrict__ m,
                              int* __restrict__ flags) {
    __shared__ int cx, cw, all01, allf32, anybf16;
    if (threadIdx.x == 0) { cx = 0; cw = 0; all01 = 1; allf32 = 1; anybf16 = 0; }
    __syncthreads();
    int lcx = 0, lcw = 0, la01 = 1, laf = 1, lab = 0;
    #pragma unroll
    for (int jj = 0; jj < 16; ++jj) {
        int i = jj * 256 + threadIdx.x;
        uint32_t vx = x[i], vw = w[i], vm = m[i];
        uint32_t ex = (vx >> 7) & 0xFFu; if (ex >= 0x70u && ex <= 0x86u) lcx++;
        uint32_t ew = (vw >> 7) & 0xFFu; if (ew >= 0x70u && ew <= 0x86u) lcw++;
        if (vm > 1u) la01 = 0;
        if (vm != 0u && vm != 0x3F800000u) laf = 0;
        if ((vm & 0xFFFFu) == 0x3F80u || (vm >> 16) == 0x3F80u) lab = 1;
    }
    atomicAdd(&cx, lcx); atomicAdd(&cw, lcw);
    if (!la01) atomicAnd(&all01, 0);
    if (!laf)  atomicAnd(&allf32, 0);
    if (lab)   atomicOr(&anybf16, 1);
    __syncthreads();
    if (threadIdx.x == 0) {
        flags[0] = (cx < 2048) ? 1 : 0;
        flags[1] = (cw < 2048) ? 1 : 0;
        int f;
        if (all01)        f = 0;
        else if (allf32)  f = 3;
        else if (anybf16) f = 2;
        else              f = 1;
        flags[2] = f;
    }
}

// ---------------------------------------------------------------------------
// Kernel 1: x fp32 -> bf16. UNCHANGED.
// ---------------------------------------------------------------------------
__global__ void xconv_kernel(const float4* __restrict__ xf,
                             uint2* __restrict__ xb2,
                             const int* __restrict__ flags) {
    if (flags[0] == 0) return;
    const int t = blockIdx.x * 256 + threadIdx.x;
    float4 a = xf[t];
    uint2 o; o.x = pk2(a.x, a.y); o.y = pk2(a.z, a.w);
    xb2[t] = o;
}

// ---------------------------------------------------------------------------
// Kernel 2: wm = bf16(w * mask). UNCHANGED.
// ---------------------------------------------------------------------------
__global__ void wmask_kernel(const void* __restrict__ w,
                             const void* __restrict__ mask,
                             const int*  __restrict__ flags,
                             uint2* __restrict__ wm2) {
    const int fw = flags[1], fm = flags[2];
    const int t = blockIdx.x * 256 + threadIdx.x;
    float wv[4];
    if (fw) {
        float4 a = ((const float4*)w)[t];
        wv[0] = a.x; wv[1] = a.y; wv[2] = a.z; wv[3] = a.w;
    } else {
        uint2 wb = ((const uint2*)w)[t];
        wv[0] = bf2f(wb.x & 0xFFFFu); wv[1] = bf2f(wb.x >> 16);
        wv[2] = bf2f(wb.y & 0xFFFFu); wv[3] = bf2f(wb.y >> 16);
    }
    int kb[4];
    if (fm == 1) {
        uint32_t m1 = ((const uint32_t*)mask)[t];
        kb[0] = (m1 & 0xFFu) != 0u;         kb[1] = ((m1 >> 8) & 0xFFu) != 0u;
        kb[2] = ((m1 >> 16) & 0xFFu) != 0u; kb[3] = (m1 >> 24) != 0u;
    } else if (fm == 2) {
        uint2 m2 = ((const uint2*)mask)[t];
        kb[0] = (m2.x & 0xFFFFu) != 0u; kb[1] = (m2.x >> 16) != 0u;
        kb[2] = (m2.y & 0xFFFFu) != 0u; kb[3] = (m2.y >> 16) != 0u;
    } else {
        uint4 m4 = ((const uint4*)mask)[t];
        kb[0] = m4.x != 0u; kb[1] = m4.y != 0u; kb[2] = m4.z != 0u; kb[3] = m4.w != 0u;
    }
    uint2 o;
    o.x = pk2(kb[0] ? wv[0] : 0.0f, kb[1] ? wv[1] : 0.0f);
    o.y = pk2(kb[2] ? wv[2] : 0.0f, kb[3] ? wv[3] : 0.0f);
    wm2[t] = o;
}

// ---------------------------------------------------------------------------
// Kernel 3: 256x256 bf16 GEMM, C = A[M,K] * B[N,K]^T — 8-phase, 1 bar/phase.
//   Per K-tile (BK=64): 4 phases (C-quadrants Q00,Q02,Q40,Q42), each ends in
//   ONE raw s_barrier. Reads are issued so their LDS service overlaps the
//   previous MFMA cluster:
//     ph1: read a_h0(8) + b_h0(4) + PREFETCH b_h1(4); stage A1(V+1); MFMA Q00
//     ph2: stage B1(V+1); MFMA Q02 (b_h1 already in flight);
//          then issue a_h1 reload(8) behind the MFMA cluster (WAR-legal)
//     ph3: stage A0(V+2); MFMA Q40 (a_h1 in flight since ph2)
//     ph4: stage B0(V+2); MFMA Q42 (all resident); vmcnt(4); barrier
//   lgkmcnt waits are left to the compiler's per-operand dependency tracking
//   (loads are IR loads, not inline asm). Barriers carry "memory" fences, so
//   load placement is quantized per phase; per-tile gl_lds issue order
//   (A1,B1,A0,B0) makes the steady-state vmcnt(4) drain exact:
//   at end of tile V it drains through B1(V+1), leaving {A0(V+2),B0(V+2)}.
//   Region-overwrite hazards: every stage-issue is >=2 barriers after the
//   certified completion of that region's last readers (checked per region).
//   Accumulation order over K unchanged -> numerics identical.
// ---------------------------------------------------------------------------
__global__ __launch_bounds__(512, 2)
void gemm_bt_kernel(const uint16_t* __restrict__ Araw,
                    const uint16_t* __restrict__ Aconv,
                    const uint16_t* __restrict__ B,
                    void* __restrict__ Cout,
                    const int* __restrict__ flags) {
    // buffer p at p*65536: A halves at +0,+16384; B halves at +32768,+49152
    __shared__ char smem[131072];

    const int fx = flags[0];
    const uint16_t* A = fx ? Aconv : Araw;

    const int bid = blockIdx.x;
    const int wid = (bid & 7) * 64 + (bid >> 3);   // T1: 512 % 8 == 0, bijective
    const int m0  = (wid >> 4) * BM;
    const int n0  = (wid & 15) * BN;

    const int tid  = threadIdx.x;
    const int lane = tid & 63;
    const int wave = tid >> 6;
    const int wm_  = wave >> 2;    // 0..1
    const int wn_  = wave & 3;     // 0..3

    // ---- staging precompute (pre-swizzled global sources, linear LDS dest) ----
    const int tL = tid >> 3;                                   // dest line 0..63
    const uint32_t srcSlot = (uint32_t)(((tid & 7) ^ (tL & 7)) * 16);
    const size_t K2 = (size_t)KDIM * 2;
    const char* aS[2][2]; const char* bS[2][2];                // [half][c]
    #pragma unroll
    for (int h = 0; h < 2; ++h)
        #pragma unroll
        for (int c = 0; c < 2; ++c) {
            const int r = h * 128 + tL + c * 64;
            aS[h][c] = (const char*)A + (size_t)(m0 + r) * K2 + srcSlot;
            bS[h][c] = (const char*)B + (size_t)(n0 + r) * K2 + srcSlot;
        }
    const uint32_t wdst = (uint32_t)(wave * 1024);  // HW adds lane*16

#define ISSUE_A(P, H, V) do {                                                   \
    const size_t kb_ = (size_t)(V) * 128;                                       \
    __builtin_amdgcn_global_load_lds(                                           \
        (__attribute__((address_space(1))) void*)(aS[H][0] + kb_),              \
        (__attribute__((address_space(3))) void*)(smem + (P)*65536 + (H)*16384 + wdst), 16, 0, 0); \
    __builtin_amdgcn_global_load_lds(                                           \
        (__attribute__((address_space(1))) void*)(aS[H][1] + kb_),              \
        (__attribute__((address_space(3))) void*)(smem + (P)*65536 + (H)*16384 + 8192 + wdst), 16, 0, 0); \
} while (0)

#define ISSUE_B(P, H, V) do {                                                   \
    const size_t kb_ = (size_t)(V) * 128;                                       \
    __builtin_amdgcn_global_load_lds(                                           \
        (__attribute__((address_space(1))) void*)(bS[H][0] + kb_),              \
        (__attribute__((address_space(3))) void*)(smem + (P)*65536 + 32768 + (H)*16384 + wdst), 16, 0, 0); \
    __builtin_amdgcn_global_load_lds(                                           \
        (__attribute__((address_space(1))) void*)(bS[H][1] + kb_),              \
        (__attribute__((address_space(3))) void*)(smem + (P)*65536 + 32768 + (H)*16384 + 8192 + wdst), 16, 0, 0); \
} while (0)

    // ---- fragment-read precompute ----
    const int fr = lane & 15;
    const int lq = lane >> 4;
    const uint32_t swz0 = (uint32_t)(((0 + lq) ^ (fr & 7)) * 16);
    const uint32_t swz1 = (uint32_t)(((4 + lq) ^ (fr & 7)) * 16);
    const uint32_t aRow = (uint32_t)((wm_ * 64 + fr) * 128);
    const uint32_t bRow = (uint32_t)((wn_ * 32 + fr) * 128);

    bf16x8 a[4][2], b[4][2];
    f32x4 acc[8][4] = {};

#define RD_A(P, H) do {                                                         \
    _Pragma("unroll")                                                           \
    for (int mi = 0; mi < 4; ++mi) {                                            \
        a[mi][0] = *(const bf16x8*)(smem + (P)*65536 + (H)*16384 + mi*2048 + aRow + swz0); \
        a[mi][1] = *(const bf16x8*)(smem + (P)*65536 + (H)*16384 + mi*2048 + aRow + swz1); \
    }                                                                           \
} while (0)

#define RD_B(P, H) do {                                                         \
    _Pragma("unroll")                                                           \
    for (int ni = 0; ni < 2; ++ni) {                                            \
        b[(H)*2+ni][0] = *(const bf16x8*)(smem + (P)*65536 + 32768 + (H)*16384 + ni*2048 + bRow + swz0); \
        b[(H)*2+ni][1] = *(const bf16x8*)(smem + (P)*65536 + 32768 + (H)*16384 + ni*2048 + bRow + swz1); \
    }                                                                           \
} while (0)

#define MFMA_Q(M0, N0) do {                                                     \
    _Pragma("unroll")                                                           \
    for (int mi = 0; mi < 4; ++mi)                                              \
        _Pragma("unroll")                                                       \
        for (int ni = 0; ni < 2; ++ni) {                                        \
            acc[(M0)+mi][(N0)+ni] = __builtin_amdgcn_mfma_f32_16x16x32_bf16(    \
                a[mi][0], b[(N0)+ni][0], acc[(M0)+mi][(N0)+ni], 0, 0, 0);       \
            acc[(M0)+mi][(N0)+ni] = __builtin_amdgcn_mfma_f32_16x16x32_bf16(    \
                a[mi][1], b[(N0)+ni][1], acc[(M0)+mi][(N0)+ni], 0, 0, 0);       \
        }                                                                       \
} while (0)

#define BAR() do { asm volatile("" ::: "memory");                               \
    __builtin_amdgcn_s_barrier();                                               \
    asm volatile("" ::: "memory"); } while (0)

#define TILE(P, V) do {                                                         \
    /* ph1: Q00 — read a_h0 + b_h0, prefetch b_h1 */                            \
    RD_A(P, 0); RD_B(P, 0); RD_B(P, 1);                                         \
    if ((V) + 1 < NT) ISSUE_A(1-(P), 1, (V)+1);                                 \
    __builtin_amdgcn_s_setprio(1);  MFMA_Q(0, 0);  __builtin_amdgcn_s_setprio(0); \
    BAR();                                                                      \
    /* ph2: Q02 — b_h1 in flight; reload a_h1 behind the MFMA cluster */        \
    if ((V) + 1 < NT) ISSUE_B(1-(P), 1, (V)+1);                                 \
    __builtin_amdgcn_s_setprio(1);  MFMA_Q(0, 2);  __builtin_amdgcn_s_setprio(0); \
    RD_A(P, 1);                                                                 \
    BAR();                                                                      \
    /* ph3: Q40 — a_h1 in flight since ph2 */                                   \
    if ((V) + 2 < NT) ISSUE_A(P, 0, (V)+2);                                     \
    __builtin_amdgcn_s_setprio(1);  MFMA_Q(4, 0);  __builtin_amdgcn_s_setprio(0); \
    BAR();                                                                      \
    /* ph4: Q42 — all operands resident */                                      \
    if ((V) + 2 < NT) ISSUE_B(P, 0, (V)+2);                                     \
    __builtin_amdgcn_s_setprio(1);  MFMA_Q(4, 2);  __builtin_amdgcn_s_setprio(0); \
    if ((V) < NT - 2) { asm volatile("s_waitcnt vmcnt(4)" ::: "memory"); }      \
    else              { asm volatile("s_waitcnt vmcnt(0)" ::: "memory"); }      \
    BAR();                                                                      \
} while (0)

    // prologue: stage tile 0 fully, certify it, then put tile 1's h0 units in
    // flight (they become the steady-state 4-outstanding tail of vmcnt(4)).
    ISSUE_A(0, 0, 0); ISSUE_B(0, 0, 0); ISSUE_B(0, 1, 0); ISSUE_A(0, 1, 0);
    asm volatile("s_waitcnt vmcnt(0)" ::: "memory");
    ISSUE_A(1, 0, 1); ISSUE_B(1, 0, 1);
    BAR();

    for (int it = 0; it < NT; it += 2) {
        TILE(0, it);
        TILE(1, it + 1);
    }

#undef TILE
#undef BAR
#undef MFMA_Q
#undef RD_B
#undef RD_A
#undef ISSUE_B
#undef ISSUE_A

    // Epilogue. D frag mapping: col = lane&15, row = (lane>>4)*4 + reg.
    // acc[m][n]: gm = m0 + (m>>2)*128 + wm_*64 + (m&3)*16;
    //            gn = n0 + (n>>1)*128 + wn_*32 + (n&1)*16.
    const int cn = lane & 15;
    const int rq = lane >> 4;
    if (fx) {
        float* C = (float*)Cout;
        #pragma unroll
        for (int mi = 0; mi < 8; ++mi)
            #pragma unroll
            for (int ni = 0; ni < 4; ++ni)
                #pragma unroll
                for (int r = 0; r < 4; ++r) {
                    const int gm = m0 + (mi >> 2) * 128 + wm_ * 64 + (mi & 3) * 16 + rq * 4 + r;
                    const int gn = n0 + (ni >> 1) * 128 + wn_ * 32 + (ni & 1) * 16 + cn;
                    C[(size_t)gm * NDIM + gn] = acc[mi][ni][r];
                }
    } else {
        __hip_bfloat16* C = (__hip_bfloat16*)Cout;
        #pragma unroll
        for (int mi = 0; mi < 8; ++mi)
            #pragma unroll
            for (int ni = 0; ni < 4; ++ni)
                #pragma unroll
                for (int r = 0; r < 4; ++r) {
                    const int gm = m0 + (mi >> 2) * 128 + wm_ * 64 + (mi & 3) * 16 + rq * 4 + r;
                    const int gn = n0 + (ni >> 1) * 128 + wn_ * 32 + (ni & 1) * 16 + cn;
                    C[(size_t)gm * NDIM + gn] = __float2bfloat16(acc[mi][ni][r]);
                }
    }
}

extern "C" void kernel_launch(void* const* d_in, const int* in_sizes, int n_in,
                              void* d_out, int out_size, void* d_ws, size_t ws_size,
                              hipStream_t stream) {
    const void* x    = d_in[0];
    const void* w    = d_in[1];
    const void* mask = d_in[2];

    int*      flags = (int*)d_ws;
    uint16_t* wm    = (uint16_t*)((char*)d_ws + 256);
    uint16_t* xb    = (uint16_t*)((char*)d_ws + 256 + (size_t)NDIM * KDIM * 2);

    detect_kernel<<<1, 256, 0, stream>>>((const uint32_t*)x, (const uint32_t*)w,
                                         (const uint32_t*)mask, flags);

    xconv_kernel<<<(BATCH * KDIM / 4) / 256, 256, 0, stream>>>(
        (const float4*)x, (uint2*)xb, flags);

    wmask_kernel<<<(NDIM * KDIM / 4) / 256, 256, 0, stream>>>(
        w, mask, flags, (uint2*)wm);

    gemm_bt_kernel<<<dim3((BATCH / BM) * (NDIM / BN)), 512, 0, stream>>>(
        (const uint16_t*)x, xb, wm, d_out, flags);
}